// Round 1
// baseline (189.011 us; speedup 1.0000x reference)
//
#include <hip/hip_runtime.h>
#include <hip/hip_bf16.h>

#define TT 2048
#define CC 8

__device__ __forceinline__ float bf2f(unsigned short u) {
    union { unsigned int ui; float f; } c;
    c.ui = ((unsigned int)u) << 16;
    return c.f;
}

// Kernel A: texture [C,T,T] f32  ->  wtex [T*T][C] bf16 (16B per texel record)
__global__ __launch_bounds__(256) void interleave_kernel(
    const float* __restrict__ tex, unsigned short* __restrict__ wtex)
{
    int idx = blockIdx.x * blockDim.x + threadIdx.x;
    if (idx >= TT * TT) return;
    union { unsigned short h[8]; uint4 u; } pack;
#pragma unroll
    for (int c = 0; c < CC; ++c) {
        float v = tex[(size_t)c * (TT * TT) + idx];
        __hip_bfloat16 b = __float2bfloat16(v);   // RNE
        pack.h[c] = *reinterpret_cast<unsigned short*>(&b);
    }
    *reinterpret_cast<uint4*>(wtex + (size_t)idx * CC) = pack.u;
}

// Kernel B: bilinear sample + MLP, one thread per sample.
template <bool USE_WS>
__global__ __launch_bounds__(256) void sample_mlp_kernel(
    const float* __restrict__ uv,
    const float* __restrict__ vd,
    const float* __restrict__ tex,                 // planar f32 (fallback path)
    const unsigned short* __restrict__ wtex,       // interleaved bf16 (fast path)
    const float* __restrict__ W1, const float* __restrict__ b1,
    const float* __restrict__ W2, const float* __restrict__ b2,
    const float* __restrict__ W3, const float* __restrict__ b3,
    float* __restrict__ out, int nB)
{
    int i = blockIdx.x * blockDim.x + threadIdx.x;
    if (i >= nB) return;

    // ---- coordinates & bilinear weights (align_corners=True, zeros padding)
    float2 uvv = *reinterpret_cast<const float2*>(uv + 2 * (size_t)i);
    float x = (uvv.x + 1.0f) * 0.5f * (float)(TT - 1);
    float y = (uvv.y + 1.0f) * 0.5f * (float)(TT - 1);
    float x0f = floorf(x), y0f = floorf(y);
    float wx1 = x - x0f, wy1 = y - y0f;
    float wx0 = 1.0f - wx1, wy0 = 1.0f - wy1;
    int x0 = (int)x0f, y0 = (int)y0f;
    int x1 = x0 + 1, y1 = y0 + 1;

    float mx0 = (x0 >= 0 && x0 <= TT - 1) ? 1.0f : 0.0f;
    float mx1 = (x1 >= 0 && x1 <= TT - 1) ? 1.0f : 0.0f;
    float my0 = (y0 >= 0 && y0 <= TT - 1) ? 1.0f : 0.0f;
    float my1 = (y1 >= 0 && y1 <= TT - 1) ? 1.0f : 0.0f;
    int x0c = min(max(x0, 0), TT - 1), x1c = min(max(x1, 0), TT - 1);
    int y0c = min(max(y0, 0), TT - 1), y1c = min(max(y1, 0), TT - 1);

    float w00 = wy0 * wx0 * my0 * mx0;
    float w01 = wy0 * wx1 * my0 * mx1;
    float w10 = wy1 * wx0 * my1 * mx0;
    float w11 = wy1 * wx1 * my1 * mx1;

    // ---- gather 4 taps x 8 channels
    float feat[CC];
    if (USE_WS) {
        const uint4* t00 = reinterpret_cast<const uint4*>(wtex + ((size_t)y0c * TT + x0c) * CC);
        const uint4* t01 = reinterpret_cast<const uint4*>(wtex + ((size_t)y0c * TT + x1c) * CC);
        const uint4* t10 = reinterpret_cast<const uint4*>(wtex + ((size_t)y1c * TT + x0c) * CC);
        const uint4* t11 = reinterpret_cast<const uint4*>(wtex + ((size_t)y1c * TT + x1c) * CC);
        uint4 a = *t00, b = *t01, c = *t10, d = *t11;
        const unsigned int* pa = reinterpret_cast<const unsigned int*>(&a);
        const unsigned int* pb = reinterpret_cast<const unsigned int*>(&b);
        const unsigned int* pc = reinterpret_cast<const unsigned int*>(&c);
        const unsigned int* pd = reinterpret_cast<const unsigned int*>(&d);
#pragma unroll
        for (int c2 = 0; c2 < 4; ++c2) {
            float a0 = bf2f((unsigned short)(pa[c2] & 0xFFFF));
            float a1 = bf2f((unsigned short)(pa[c2] >> 16));
            float b0 = bf2f((unsigned short)(pb[c2] & 0xFFFF));
            float b1v = bf2f((unsigned short)(pb[c2] >> 16));
            float c0 = bf2f((unsigned short)(pc[c2] & 0xFFFF));
            float c1 = bf2f((unsigned short)(pc[c2] >> 16));
            float d0 = bf2f((unsigned short)(pd[c2] & 0xFFFF));
            float d1 = bf2f((unsigned short)(pd[c2] >> 16));
            feat[2 * c2]     = fmaf(w00, a0, fmaf(w01, b0, fmaf(w10, c0, w11 * d0)));
            feat[2 * c2 + 1] = fmaf(w00, a1, fmaf(w01, b1v, fmaf(w10, c1, w11 * d1)));
        }
    } else {
#pragma unroll
        for (int c2 = 0; c2 < CC; ++c2) {
            const float* tp = tex + (size_t)c2 * (TT * TT);
            float a0 = tp[(size_t)y0c * TT + x0c];
            float b0 = tp[(size_t)y0c * TT + x1c];
            float c0 = tp[(size_t)y1c * TT + x0c];
            float d0 = tp[(size_t)y1c * TT + x1c];
            feat[c2] = fmaf(w00, a0, fmaf(w01, b0, fmaf(w10, c0, w11 * d0)));
        }
    }

    // ---- MLP input: [feat(8), viewdirs(3)]
    float xin[11];
#pragma unroll
    for (int c2 = 0; c2 < CC; ++c2) xin[c2] = feat[c2];
    xin[8]  = vd[3 * (size_t)i + 0];
    xin[9]  = vd[3 * (size_t)i + 1];
    xin[10] = vd[3 * (size_t)i + 2];

    // ---- layer 1: 11 -> 16, relu. Weight indices are compile-time constants
    // -> uniform addresses -> s_load + SGPR operand on v_fma.
    float h1[16];
#pragma unroll
    for (int k = 0; k < 16; ++k) {
        float a = b1[k];
#pragma unroll
        for (int j = 0; j < 11; ++j) a = fmaf(xin[j], W1[k * 11 + j], a);
        h1[k] = fmaxf(a, 0.0f);
    }
    // ---- layer 2: 16 -> 16, relu
    float h2[16];
#pragma unroll
    for (int k = 0; k < 16; ++k) {
        float a = b2[k];
#pragma unroll
        for (int j = 0; j < 16; ++j) a = fmaf(h1[j], W2[k * 16 + j], a);
        h2[k] = fmaxf(a, 0.0f);
    }
    // ---- layer 3: 16 -> 3, sigmoid
#pragma unroll
    for (int k = 0; k < 3; ++k) {
        float a = b3[k];
#pragma unroll
        for (int j = 0; j < 16; ++j) a = fmaf(h2[j], W3[k * 16 + j], a);
        out[3 * (size_t)i + k] = 1.0f / (1.0f + __expf(-a));
    }
}

extern "C" void kernel_launch(void* const* d_in, const int* in_sizes, int n_in,
                              void* d_out, int out_size, void* d_ws, size_t ws_size,
                              hipStream_t stream)
{
    const float* uv  = (const float*)d_in[0];
    const float* vd  = (const float*)d_in[1];
    const float* tex = (const float*)d_in[2];
    const float* W1  = (const float*)d_in[3];
    const float* b1  = (const float*)d_in[4];
    const float* W2  = (const float*)d_in[5];
    const float* b2  = (const float*)d_in[6];
    const float* W3  = (const float*)d_in[7];
    const float* b3  = (const float*)d_in[8];
    float* out = (float*)d_out;
    int nB = in_sizes[0] / 2;

    const size_t need = (size_t)TT * TT * CC * sizeof(unsigned short);  // 64 MiB
    if (ws_size >= need) {
        unsigned short* wtex = (unsigned short*)d_ws;
        interleave_kernel<<<(TT * TT) / 256, 256, 0, stream>>>(tex, wtex);
        sample_mlp_kernel<true><<<(nB + 255) / 256, 256, 0, stream>>>(
            uv, vd, tex, wtex, W1, b1, W2, b2, W3, b3, out, nB);
    } else {
        sample_mlp_kernel<false><<<(nB + 255) / 256, 256, 0, stream>>>(
            uv, vd, tex, nullptr, W1, b1, W2, b2, W3, b3, out, nB);
    }
}

// Round 2
// 176.722 us; speedup vs baseline: 1.0695x; 1.0695x over previous
//
#include <hip/hip_runtime.h>
#include <hip/hip_bf16.h>

#define TT 2048
#define CC 8
#define R0 1023          // hot-region origin (uv in [0,1] -> taps in [1023,2047])
#define NRG 1025         // hot-region extent
#define SPT 8            // samples per thread

typedef short short8v __attribute__((ext_vector_type(8)));
typedef float float4v __attribute__((ext_vector_type(4)));

static __device__ __forceinline__ unsigned short f2bf(float f) {
    __hip_bfloat16 b = __float2bfloat16(f);   // RNE
    return *reinterpret_cast<unsigned short*>(&b);
}
static __device__ __forceinline__ float bf2f(unsigned short u) {
    union { unsigned int ui; float f; } c; c.ui = ((unsigned int)u) << 16; return c.f;
}

// Kernel A: interleave+compress ONLY the hot region [R0..R0+NRG) x [R0..R0+NRG)
// into wtex[(y-R0)*NRG + (x-R0)][8] bf16 (16B records).
__global__ __launch_bounds__(256) void interleave_kernel(
    const float* __restrict__ tex, unsigned short* __restrict__ wtex)
{
    int idx = blockIdx.x * 256 + threadIdx.x;
    if (idx >= NRG * NRG) return;
    int yy = idx / NRG;
    int xx = idx - yy * NRG;
    size_t src = (size_t)(R0 + yy) * TT + (size_t)(R0 + xx);
    union { unsigned short h[8]; uint4 u; } p;
#pragma unroll
    for (int c = 0; c < CC; ++c) p.h[c] = f2bf(tex[(size_t)c * (TT * TT) + src]);
    *reinterpret_cast<uint4*>(wtex + (size_t)idx * CC) = p.u;
}

// Kernel B: bilinear sample + MFMA MLP. One wave = 64 samples per iteration.
template <bool USE_WS>
__global__ __launch_bounds__(256) void sample_mlp_kernel(
    const float* __restrict__ uv,
    const float* __restrict__ vd,
    const float* __restrict__ tex,            // planar f32 (fallback taps)
    const unsigned short* __restrict__ wtex,  // hot-region interleaved bf16
    const float* __restrict__ W1, const float* __restrict__ b1,
    const float* __restrict__ W2, const float* __restrict__ b2,
    const float* __restrict__ W3, const float* __restrict__ b3,
    float* __restrict__ out, int nB)
{
    // Per-wave LDS: two [64 samples][16 k] bf16 tiles (xin / hidden), 16B-granule
    // XOR-swizzled by sample parity to break the 32B-row bank pattern.
    __shared__ unsigned short lds[4][2][64 * 16];   // 16 KiB/block
    const int tid  = threadIdx.x;
    const int wave = tid >> 6, lane = tid & 63;
    const int col  = lane & 15, kg = lane >> 4;     // MFMA fragment coords
    unsigned short* xbuf = &lds[wave][0][0];
    unsigned short* hbuf = &lds[wave][1][0];

    // ---- A-fragments (weights, bf16) + C-init (bias). Loaded once per thread,
    // amortized over SPT samples. A: row = lane&15, k = (lane>>4)*8 + i.
    short8v a1, a2, a3;
#pragma unroll
    for (int i2 = 0; i2 < 8; ++i2) {
        int k = kg * 8 + i2;
        a1[i2] = (short)((k < 11) ? f2bf(W1[col * 11 + k]) : 0);
        a2[i2] = (short)((k < 16) ? f2bf(W2[col * 16 + k]) : 0);
        a3[i2] = (short)((col < 3 && k < 16) ? f2bf(W3[col * 16 + k]) : 0);
    }
    float4v c1, c2, c3;
#pragma unroll
    for (int r = 0; r < 4; ++r) {
        int rr = kg * 4 + r;
        c1[r] = b1[rr];
        c2[r] = b2[rr];
        c3[r] = (rr < 3) ? b3[rr] : 0.0f;
    }

    const long long base = (long long)blockIdx.x * (256 * SPT);
    const unsigned swzW = (unsigned)(lane & 1);   // write-side swizzle (row = lane)
    const unsigned swzR = (unsigned)(col  & 1);   // read-side swizzle (row = g*16+col)

    for (int t = 0; t < SPT; ++t) {
        const long long i = base + (long long)t * 256 + tid;
        const bool act = (i < nB);

        // ---- coordinates & bilinear weights (align_corners=True, zeros pad)
        float2 uvv = act ? *reinterpret_cast<const float2*>(uv + 2 * i)
                         : make_float2(-2.0f, -2.0f);
        float x = (uvv.x + 1.0f) * 0.5f * (float)(TT - 1);
        float y = (uvv.y + 1.0f) * 0.5f * (float)(TT - 1);
        float x0f = floorf(x), y0f = floorf(y);
        float wx1 = x - x0f, wy1 = y - y0f;
        float wx0 = 1.0f - wx1, wy0 = 1.0f - wy1;
        int x0 = (int)x0f, y0 = (int)y0f;
        int x1 = x0 + 1, y1 = y0 + 1;
        float mx0 = (x0 >= 0 && x0 <= TT - 1) ? 1.0f : 0.0f;
        float mx1 = (x1 >= 0 && x1 <= TT - 1) ? 1.0f : 0.0f;
        float my0 = (y0 >= 0 && y0 <= TT - 1) ? 1.0f : 0.0f;
        float my1 = (y1 >= 0 && y1 <= TT - 1) ? 1.0f : 0.0f;
        int x0c = min(max(x0, 0), TT - 1), x1c = min(max(x1, 0), TT - 1);
        int y0c = min(max(y0, 0), TT - 1), y1c = min(max(y1, 0), TT - 1);
        float w00 = wy0 * wx0 * my0 * mx0;
        float w01 = wy0 * wx1 * my0 * mx1;
        float w10 = wy1 * wx0 * my1 * mx0;
        float w11 = wy1 * wx1 * my1 * mx1;

        // ---- gather 4 taps x 8 channels
        float feat[CC];
        const bool inreg = USE_WS && (x0c >= R0) && (y0c >= R0);
        if (inreg) {
            int ry0 = y0c - R0, ry1 = y1c - R0, rx0 = x0c - R0, rx1 = x1c - R0;
            uint4 A = *reinterpret_cast<const uint4*>(wtex + ((size_t)ry0 * NRG + rx0) * CC);
            uint4 Bv = *reinterpret_cast<const uint4*>(wtex + ((size_t)ry0 * NRG + rx1) * CC);
            uint4 Cv = *reinterpret_cast<const uint4*>(wtex + ((size_t)ry1 * NRG + rx0) * CC);
            uint4 Dv = *reinterpret_cast<const uint4*>(wtex + ((size_t)ry1 * NRG + rx1) * CC);
            const unsigned int* pa = reinterpret_cast<const unsigned int*>(&A);
            const unsigned int* pb = reinterpret_cast<const unsigned int*>(&Bv);
            const unsigned int* pc = reinterpret_cast<const unsigned int*>(&Cv);
            const unsigned int* pd = reinterpret_cast<const unsigned int*>(&Dv);
#pragma unroll
            for (int c2 = 0; c2 < 4; ++c2) {
                float a0 = bf2f((unsigned short)(pa[c2] & 0xFFFF));
                float a1v = bf2f((unsigned short)(pa[c2] >> 16));
                float b0 = bf2f((unsigned short)(pb[c2] & 0xFFFF));
                float b1v = bf2f((unsigned short)(pb[c2] >> 16));
                float c0 = bf2f((unsigned short)(pc[c2] & 0xFFFF));
                float c1v = bf2f((unsigned short)(pc[c2] >> 16));
                float d0 = bf2f((unsigned short)(pd[c2] & 0xFFFF));
                float d1v = bf2f((unsigned short)(pd[c2] >> 16));
                feat[2 * c2]     = fmaf(w00, a0, fmaf(w01, b0, fmaf(w10, c0, w11 * d0)));
                feat[2 * c2 + 1] = fmaf(w00, a1v, fmaf(w01, b1v, fmaf(w10, c1v, w11 * d1v)));
            }
        } else {
            // fully general planar fallback (also taken by padded/inactive lanes)
#pragma unroll
            for (int c2 = 0; c2 < CC; ++c2) {
                const float* tp = tex + (size_t)c2 * (TT * TT);
                float a0 = tp[(size_t)y0c * TT + x0c];
                float b0 = tp[(size_t)y0c * TT + x1c];
                float c0 = tp[(size_t)y1c * TT + x0c];
                float d0 = tp[(size_t)y1c * TT + x1c];
                feat[c2] = fmaf(w00, a0, fmaf(w01, b0, fmaf(w10, c0, w11 * d0)));
            }
        }

        // ---- pack xin = [feat(8), vd(3), 0*5] as bf16 into LDS [64][16]
        float v0 = act ? vd[3 * i + 0] : 0.0f;
        float v1 = act ? vd[3 * i + 1] : 0.0f;
        float v2 = act ? vd[3 * i + 2] : 0.0f;
        unsigned int xw0 = (unsigned)f2bf(feat[0]) | ((unsigned)f2bf(feat[1]) << 16);
        unsigned int xw1 = (unsigned)f2bf(feat[2]) | ((unsigned)f2bf(feat[3]) << 16);
        unsigned int xw2 = (unsigned)f2bf(feat[4]) | ((unsigned)f2bf(feat[5]) << 16);
        unsigned int xw3 = (unsigned)f2bf(feat[6]) | ((unsigned)f2bf(feat[7]) << 16);
        unsigned int xw4 = (unsigned)f2bf(v0)      | ((unsigned)f2bf(v1)      << 16);
        unsigned int xw5 = (unsigned)f2bf(v2);
        {
            unsigned short* rowp = xbuf + lane * 16;
            *reinterpret_cast<uint4*>(rowp + ((0u ^ swzW) << 3)) = make_uint4(xw0, xw1, xw2, xw3);
            *reinterpret_cast<uint4*>(rowp + ((1u ^ swzW) << 3)) = make_uint4(xw4, xw5, 0u, 0u);
        }

        // ---- 3-layer MLP via MFMA, per 16-sample group
#pragma unroll
        for (int g = 0; g < 4; ++g) {
            const int sg = g * 16 + col;                 // this lane's B-column sample
            unsigned short* xrow = xbuf + sg * 16;
            unsigned short* hrow = hbuf + sg * 16;

            // layer 1: 11 -> 16, relu
            short8v bfr = {0, 0, 0, 0, 0, 0, 0, 0};
            if (kg < 2) bfr = *reinterpret_cast<const short8v*>(xrow + (((unsigned)kg ^ swzR) << 3));
            float4v d1 = __builtin_amdgcn_mfma_f32_16x16x32_bf16(a1, bfr, c1, 0, 0, 0);
            {
                unsigned h0 = (unsigned)f2bf(fmaxf(d1[0], 0.0f)) | ((unsigned)f2bf(fmaxf(d1[1], 0.0f)) << 16);
                unsigned h1w = (unsigned)f2bf(fmaxf(d1[2], 0.0f)) | ((unsigned)f2bf(fmaxf(d1[3], 0.0f)) << 16);
                // write rows kg*4..kg*4+3 of sample sg: 8B at k-offset kg*4
                unsigned short* wp = hrow + ((((unsigned)(kg >> 1)) ^ swzR) << 3) + (kg & 1) * 4;
                *reinterpret_cast<uint2*>(wp) = make_uint2(h0, h1w);
            }
            // layer 2: 16 -> 16, relu
            short8v b2f = {0, 0, 0, 0, 0, 0, 0, 0};
            if (kg < 2) b2f = *reinterpret_cast<const short8v*>(hrow + (((unsigned)kg ^ swzR) << 3));
            float4v d2 = __builtin_amdgcn_mfma_f32_16x16x32_bf16(a2, b2f, c2, 0, 0, 0);
            {
                unsigned h0 = (unsigned)f2bf(fmaxf(d2[0], 0.0f)) | ((unsigned)f2bf(fmaxf(d2[1], 0.0f)) << 16);
                unsigned h1w = (unsigned)f2bf(fmaxf(d2[2], 0.0f)) | ((unsigned)f2bf(fmaxf(d2[3], 0.0f)) << 16);
                unsigned short* wp = xrow + ((((unsigned)(kg >> 1)) ^ swzR) << 3) + (kg & 1) * 4;
                *reinterpret_cast<uint2*>(wp) = make_uint2(h0, h1w);   // xin no longer needed
            }
            // layer 3: 16 -> 3, sigmoid
            short8v b3f = {0, 0, 0, 0, 0, 0, 0, 0};
            if (kg < 2) b3f = *reinterpret_cast<const short8v*>(xrow + (((unsigned)kg ^ swzR) << 3));
            float4v d3 = __builtin_amdgcn_mfma_f32_16x16x32_bf16(a3, b3f, c3, 0, 0, 0);

            if (kg == 0) {   // lanes 0..15 hold rows 0..3 (rgb = rows 0..2) of sample sg
                long long gidx = base + (long long)t * 256 + wave * 64 + sg;
                if (gidx < nB) {
                    float o0 = 1.0f / (1.0f + __expf(-d3[0]));
                    float o1 = 1.0f / (1.0f + __expf(-d3[1]));
                    float o2 = 1.0f / (1.0f + __expf(-d3[2]));
                    out[3 * gidx + 0] = o0;
                    out[3 * gidx + 1] = o1;
                    out[3 * gidx + 2] = o2;
                }
            }
        }
    }
}

extern "C" void kernel_launch(void* const* d_in, const int* in_sizes, int n_in,
                              void* d_out, int out_size, void* d_ws, size_t ws_size,
                              hipStream_t stream)
{
    const float* uv  = (const float*)d_in[0];
    const float* vd  = (const float*)d_in[1];
    const float* tex = (const float*)d_in[2];
    const float* W1  = (const float*)d_in[3];
    const float* b1  = (const float*)d_in[4];
    const float* W2  = (const float*)d_in[5];
    const float* b2  = (const float*)d_in[6];
    const float* W3  = (const float*)d_in[7];
    const float* b3  = (const float*)d_in[8];
    float* out = (float*)d_out;
    int nB = in_sizes[0] / 2;

    const size_t need = (size_t)NRG * NRG * CC * sizeof(unsigned short);  // ~16.8 MiB
    int nblk = (nB + 256 * SPT - 1) / (256 * SPT);
    if (ws_size >= need) {
        unsigned short* wtex = (unsigned short*)d_ws;
        interleave_kernel<<<(NRG * NRG + 255) / 256, 256, 0, stream>>>(tex, wtex);
        sample_mlp_kernel<true><<<nblk, 256, 0, stream>>>(
            uv, vd, tex, wtex, W1, b1, W2, b2, W3, b3, out, nB);
    } else {
        sample_mlp_kernel<false><<<nblk, 256, 0, stream>>>(
            uv, vd, tex, nullptr, W1, b1, W2, b2, W3, b3, out, nB);
    }
}

// Round 3
// 169.923 us; speedup vs baseline: 1.1123x; 1.0400x over previous
//
#include <hip/hip_runtime.h>
#include <hip/hip_bf16.h>

#define TT 2048
#define CC 8
#define R0 1023          // hot-region origin (uv in [0,1] -> taps in [1023,2047])
#define NRG 1025         // hot-region extent

// packed-weight layout (floats) inside d_ws at WPOFF
#define OW1 0            // 8 pairs x 11 j  -> 176
#define OB1 176          // 8 pairs         -> 16
#define OW2 192          // 8 pairs x 16 j  -> 256
#define OB2 448          // 8 pairs         -> 16
#define OW3 464          // 2 pairs x 16 j  -> 64 (row 3 zero-padded)
#define OB3 528          // 2 pairs         -> 4
#define WPFLOATS 532

typedef float f2 __attribute__((ext_vector_type(2)));

static __device__ __forceinline__ unsigned short f2bf(float f) {
    __hip_bfloat16 b = __float2bfloat16(f);   // RNE
    return *reinterpret_cast<unsigned short*>(&b);
}
static __device__ __forceinline__ f2 bfp(unsigned u) {   // decode 2 packed bf16
    union { unsigned q; float f; } lo, hi;
    lo.q = u << 16; hi.q = u & 0xFFFF0000u;
    f2 r; r.x = lo.f; r.y = hi.f; return r;
}
static __device__ __forceinline__ f2 fma2(f2 a, f2 b, f2 c) {
#if __has_builtin(__builtin_elementwise_fma)
    return __builtin_elementwise_fma(a, b, c);
#else
    f2 r; r.x = fmaf(a.x, b.x, c.x); r.y = fmaf(a.y, b.y, c.y); return r;
#endif
}
static __device__ __forceinline__ f2 relu2(f2 a) {
#if __has_builtin(__builtin_elementwise_max)
    f2 z; z.x = 0.0f; z.y = 0.0f;
    return __builtin_elementwise_max(a, z);
#else
    f2 r; r.x = fmaxf(a.x, 0.f); r.y = fmaxf(a.y, 0.f); return r;
#endif
}

// ---------------- Kernel A: hot-region interleave+compress ----------------
__global__ __launch_bounds__(256) void interleave_kernel(
    const float* __restrict__ tex, unsigned short* __restrict__ wtex)
{
    int idx = blockIdx.x * 256 + threadIdx.x;
    if (idx >= NRG * NRG) return;
    int yy = idx / NRG;
    int xx = idx - yy * NRG;
    size_t src = (size_t)(R0 + yy) * TT + (size_t)(R0 + xx);
    union { unsigned short h[8]; uint4 u; } p;
#pragma unroll
    for (int c = 0; c < CC; ++c) p.h[c] = f2bf(tex[(size_t)c * (TT * TT) + src]);
    *reinterpret_cast<uint4*>(wtex + (size_t)idx * CC) = p.u;
}

// ---------------- Kernel A2: pack weights pair-major for v_pk_fma_f32 -----
__global__ __launch_bounds__(256) void prep_kernel(
    const float* __restrict__ W1, const float* __restrict__ b1,
    const float* __restrict__ W2, const float* __restrict__ b2,
    const float* __restrict__ W3, const float* __restrict__ b3,
    float* __restrict__ wp)
{
    int t = threadIdx.x;
    for (int i = t; i < 88; i += 256) { int p = i / 11, j = i - p * 11;
        wp[OW1 + 2 * i]     = W1[(2 * p) * 11 + j];
        wp[OW1 + 2 * i + 1] = W1[(2 * p + 1) * 11 + j]; }
    for (int i = t; i < 8; i += 256) {
        wp[OB1 + 2 * i] = b1[2 * i]; wp[OB1 + 2 * i + 1] = b1[2 * i + 1]; }
    for (int i = t; i < 128; i += 256) { int p = i >> 4, j = i & 15;
        wp[OW2 + 2 * i]     = W2[(2 * p) * 16 + j];
        wp[OW2 + 2 * i + 1] = W2[(2 * p + 1) * 16 + j]; }
    for (int i = t; i < 8; i += 256) {
        wp[OB2 + 2 * i] = b2[2 * i]; wp[OB2 + 2 * i + 1] = b2[2 * i + 1]; }
    for (int i = t; i < 32; i += 256) { int p = i >> 4, j = i & 15;
        int r0 = 2 * p, r1 = 2 * p + 1;
        wp[OW3 + 2 * i]     = (r0 < 3) ? W3[r0 * 16 + j] : 0.0f;
        wp[OW3 + 2 * i + 1] = (r1 < 3) ? W3[r1 * 16 + j] : 0.0f; }
    if (t == 0) { wp[OB3] = b3[0]; wp[OB3 + 1] = b3[1]; wp[OB3 + 2] = b3[2]; wp[OB3 + 3] = 0.0f; }
}

// ---------------- helpers for the sample kernel ----------------
static __device__ __forceinline__ bool fast_coords(float ux, float uy, int& o00, float w[4])
{
    float px = (ux + 1.0f) * 1023.5f;     // == ((u+1)*0.5)*(T-1), same rounding
    float py = (uy + 1.0f) * 1023.5f;
    float fx = floorf(px), fy = floorf(py);
    float wx1 = px - fx, wy1 = py - fy;
    float wx0 = 1.0f - wx1, wy0 = 1.0f - wy1;
    int x0 = (int)fx, y0 = (int)fy;
    w[0] = wy0 * wx0; w[1] = wy0 * wx1; w[2] = wy1 * wx0; w[3] = wy1 * wx1;
    o00 = (y0 - R0) * NRG + (x0 - R0);
    return (x0 >= R0) & (y0 >= R0) & (x0 < TT - 1) & (y0 < TT - 1);
}

static __device__ __forceinline__ void blend4(
    const uint4& A, const uint4& B, const uint4& C, const uint4& D,
    const float w[4], float feat[8])
{
    f2 w0, w1, w2, w3;
    w0.x = w0.y = w[0]; w1.x = w1.y = w[1]; w2.x = w2.y = w[2]; w3.x = w3.y = w[3];
    const unsigned* pa = reinterpret_cast<const unsigned*>(&A);
    const unsigned* pb = reinterpret_cast<const unsigned*>(&B);
    const unsigned* pc = reinterpret_cast<const unsigned*>(&C);
    const unsigned* pd = reinterpret_cast<const unsigned*>(&D);
#pragma unroll
    for (int c = 0; c < 4; ++c) {
        f2 r = bfp(pd[c]) * w3;
        r = fma2(bfp(pc[c]), w2, r);
        r = fma2(bfp(pb[c]), w1, r);
        r = fma2(bfp(pa[c]), w0, r);
        feat[2 * c] = r.x; feat[2 * c + 1] = r.y;
    }
}

// fully-general bilinear (zeros padding) from planar f32 texture
static __device__ __forceinline__ void gen_feat(
    const float* __restrict__ tex, float ux, float uy, float feat[8])
{
    float px = (ux + 1.0f) * 1023.5f;
    float py = (uy + 1.0f) * 1023.5f;
    float fx = floorf(px), fy = floorf(py);
    float wx1 = px - fx, wy1 = py - fy;
    float wx0 = 1.0f - wx1, wy0 = 1.0f - wy1;
    int x0 = (int)fx, y0 = (int)fy, x1 = x0 + 1, y1 = y0 + 1;
    float mx0 = (x0 >= 0 && x0 <= TT - 1) ? 1.0f : 0.0f;
    float mx1 = (x1 >= 0 && x1 <= TT - 1) ? 1.0f : 0.0f;
    float my0 = (y0 >= 0 && y0 <= TT - 1) ? 1.0f : 0.0f;
    float my1 = (y1 >= 0 && y1 <= TT - 1) ? 1.0f : 0.0f;
    int x0c = min(max(x0, 0), TT - 1), x1c = min(max(x1, 0), TT - 1);
    int y0c = min(max(y0, 0), TT - 1), y1c = min(max(y1, 0), TT - 1);
    float w00 = wy0 * wx0 * my0 * mx0, w01 = wy0 * wx1 * my0 * mx1;
    float w10 = wy1 * wx0 * my1 * mx0, w11 = wy1 * wx1 * my1 * mx1;
#pragma unroll
    for (int c = 0; c < CC; ++c) {
        const float* tp = tex + (size_t)c * (TT * TT);
        float a0 = tp[(size_t)y0c * TT + x0c];
        float b0 = tp[(size_t)y0c * TT + x1c];
        float c0 = tp[(size_t)y1c * TT + x0c];
        float d0 = tp[(size_t)y1c * TT + x1c];
        feat[c] = fmaf(w00, a0, fmaf(w01, b0, fmaf(w10, c0, w11 * d0)));
    }
}

static __device__ __forceinline__ void mlp_packed(
    const float* __restrict__ wp, const float x[11], float rgb[3])
{
    f2 xb[11];
#pragma unroll
    for (int j = 0; j < 11; ++j) { xb[j].x = x[j]; xb[j].y = x[j]; }
    float h1[16];
#pragma unroll
    for (int p = 0; p < 8; ++p) {
        f2 acc = *reinterpret_cast<const f2*>(wp + OB1 + 2 * p);
#pragma unroll
        for (int j = 0; j < 11; ++j)
            acc = fma2(xb[j], *reinterpret_cast<const f2*>(wp + OW1 + 2 * (p * 11 + j)), acc);
        acc = relu2(acc);
        h1[2 * p] = acc.x; h1[2 * p + 1] = acc.y;
    }
    f2 hb[16];
#pragma unroll
    for (int j = 0; j < 16; ++j) { hb[j].x = h1[j]; hb[j].y = h1[j]; }
    float h2[16];
#pragma unroll
    for (int p = 0; p < 8; ++p) {
        f2 acc = *reinterpret_cast<const f2*>(wp + OB2 + 2 * p);
#pragma unroll
        for (int j = 0; j < 16; ++j)
            acc = fma2(hb[j], *reinterpret_cast<const f2*>(wp + OW2 + 2 * (p * 16 + j)), acc);
        acc = relu2(acc);
        h2[2 * p] = acc.x; h2[2 * p + 1] = acc.y;
    }
    f2 o01 = *reinterpret_cast<const f2*>(wp + OB3);
    f2 o23 = *reinterpret_cast<const f2*>(wp + OB3 + 2);
#pragma unroll
    for (int j = 0; j < 16; ++j) {
        f2 hB; hB.x = h2[j]; hB.y = h2[j];
        o01 = fma2(hB, *reinterpret_cast<const f2*>(wp + OW3 + 2 * j), o01);
        o23 = fma2(hB, *reinterpret_cast<const f2*>(wp + OW3 + 2 * (16 + j)), o23);
    }
    rgb[0] = o01.x; rgb[1] = o01.y; rgb[2] = o23.x;
#pragma unroll
    for (int k = 0; k < 3; ++k)
        rgb[k] = __builtin_amdgcn_rcpf(1.0f + __expf(-rgb[k]));
}

static __device__ __forceinline__ void mlp_scalar(
    const float* __restrict__ W1, const float* __restrict__ b1,
    const float* __restrict__ W2, const float* __restrict__ b2,
    const float* __restrict__ W3, const float* __restrict__ b3,
    const float x[11], float rgb[3])
{
    float h1[16];
#pragma unroll
    for (int k = 0; k < 16; ++k) {
        float a = b1[k];
#pragma unroll
        for (int j = 0; j < 11; ++j) a = fmaf(x[j], W1[k * 11 + j], a);
        h1[k] = fmaxf(a, 0.0f);
    }
    float h2[16];
#pragma unroll
    for (int k = 0; k < 16; ++k) {
        float a = b2[k];
#pragma unroll
        for (int j = 0; j < 16; ++j) a = fmaf(h1[j], W2[k * 16 + j], a);
        h2[k] = fmaxf(a, 0.0f);
    }
#pragma unroll
    for (int k = 0; k < 3; ++k) {
        float a = b3[k];
#pragma unroll
        for (int j = 0; j < 16; ++j) a = fmaf(h2[j], W3[k * 16 + j], a);
        rgb[k] = __builtin_amdgcn_rcpf(1.0f + __expf(-a));
    }
}

// ---------------- Kernel B: 2 samples/thread, batched gathers, packed MLP --
template <bool USE_WS>
__global__ __launch_bounds__(256) void sample_mlp_kernel(
    const float* __restrict__ uv, const float* __restrict__ vd,
    const float* __restrict__ tex, const unsigned short* __restrict__ wtex,
    const float* __restrict__ wp,
    const float* __restrict__ W1, const float* __restrict__ b1,
    const float* __restrict__ W2, const float* __restrict__ b2,
    const float* __restrict__ W3, const float* __restrict__ b3,
    float* __restrict__ out, int nB)
{
    long long g = (long long)blockIdx.x * 256 + threadIdx.x;
    long long s0 = 2 * g;
    if (s0 >= nB) return;
    const bool act1 = (s0 + 1 < nB);

    float4 uv4;
    if (act1) {
        uv4 = *reinterpret_cast<const float4*>(uv + 2 * s0);   // 16B aligned
    } else {
        float2 t0 = *reinterpret_cast<const float2*>(uv + 2 * s0);
        uv4.x = t0.x; uv4.y = t0.y; uv4.z = -3.0f; uv4.w = -3.0f;  // pad -> masks 0
    }

    float vA[3], vB[3];
    if (act1) {
        float2 a = *reinterpret_cast<const float2*>(vd + 3 * s0);
        float2 b = *reinterpret_cast<const float2*>(vd + 3 * s0 + 2);
        float2 c = *reinterpret_cast<const float2*>(vd + 3 * s0 + 4);
        vA[0] = a.x; vA[1] = a.y; vA[2] = b.x;
        vB[0] = b.y; vB[1] = c.x; vB[2] = c.y;
    } else {
        vA[0] = vd[3 * s0]; vA[1] = vd[3 * s0 + 1]; vA[2] = vd[3 * s0 + 2];
        vB[0] = vB[1] = vB[2] = 0.0f;
    }

    float featA[8], featB[8];
    if (USE_WS) {
        int oA, oB; float wA[4], wB[4];
        bool fA = fast_coords(uv4.x, uv4.y, oA, wA);
        bool fB = fast_coords(uv4.z, uv4.w, oB, wB);
        if (fA & fB) {
            const uint4* base = reinterpret_cast<const uint4*>(wtex);
            // 8 independent gathers issued together -> max memory ILP
            uint4 A00 = base[oA],       A01 = base[oA + 1];
            uint4 A10 = base[oA + NRG], A11 = base[oA + NRG + 1];
            uint4 B00 = base[oB],       B01 = base[oB + 1];
            uint4 B10 = base[oB + NRG], B11 = base[oB + NRG + 1];
            blend4(A00, A01, A10, A11, wA, featA);
            blend4(B00, B01, B10, B11, wB, featB);
        } else {
            gen_feat(tex, uv4.x, uv4.y, featA);
            gen_feat(tex, uv4.z, uv4.w, featB);
        }
    } else {
        gen_feat(tex, uv4.x, uv4.y, featA);
        gen_feat(tex, uv4.z, uv4.w, featB);
    }

    float xA[11], xB[11];
#pragma unroll
    for (int c = 0; c < 8; ++c) { xA[c] = featA[c]; xB[c] = featB[c]; }
    xA[8] = vA[0]; xA[9] = vA[1]; xA[10] = vA[2];
    xB[8] = vB[0]; xB[9] = vB[1]; xB[10] = vB[2];

    float rgbA[3], rgbB[3];
    if (USE_WS) {
        mlp_packed(wp, xA, rgbA);
        mlp_packed(wp, xB, rgbB);
    } else {
        mlp_scalar(W1, b1, W2, b2, W3, b3, xA, rgbA);
        mlp_scalar(W1, b1, W2, b2, W3, b3, xB, rgbB);
    }

    if (act1) {
        f2 w0, w1, w2;
        w0.x = rgbA[0]; w0.y = rgbA[1];
        w1.x = rgbA[2]; w1.y = rgbB[0];
        w2.x = rgbB[1]; w2.y = rgbB[2];
        *reinterpret_cast<f2*>(out + 3 * s0)     = w0;
        *reinterpret_cast<f2*>(out + 3 * s0 + 2) = w1;
        *reinterpret_cast<f2*>(out + 3 * s0 + 4) = w2;
    } else {
        out[3 * s0] = rgbA[0]; out[3 * s0 + 1] = rgbA[1]; out[3 * s0 + 2] = rgbA[2];
    }
}

extern "C" void kernel_launch(void* const* d_in, const int* in_sizes, int n_in,
                              void* d_out, int out_size, void* d_ws, size_t ws_size,
                              hipStream_t stream)
{
    const float* uv  = (const float*)d_in[0];
    const float* vd  = (const float*)d_in[1];
    const float* tex = (const float*)d_in[2];
    const float* W1  = (const float*)d_in[3];
    const float* b1  = (const float*)d_in[4];
    const float* W2  = (const float*)d_in[5];
    const float* b2  = (const float*)d_in[6];
    const float* W3  = (const float*)d_in[7];
    const float* b3  = (const float*)d_in[8];
    float* out = (float*)d_out;
    int nB = in_sizes[0] / 2;

    const size_t wtexBytes = (size_t)NRG * NRG * CC * sizeof(unsigned short);  // 16.8 MB
    const size_t wpOff = (wtexBytes + 15) & ~(size_t)15;
    const size_t need = wpOff + WPFLOATS * sizeof(float);
    int nblk = (int)((nB + 511) / 512);   // 2 samples per thread

    if (ws_size >= need) {
        unsigned short* wtex = (unsigned short*)d_ws;
        float* wp = (float*)((char*)d_ws + wpOff);
        prep_kernel<<<1, 256, 0, stream>>>(W1, b1, W2, b2, W3, b3, wp);
        interleave_kernel<<<(NRG * NRG + 255) / 256, 256, 0, stream>>>(tex, wtex);
        sample_mlp_kernel<true><<<nblk, 256, 0, stream>>>(
            uv, vd, tex, wtex, wp, W1, b1, W2, b2, W3, b3, out, nB);
    } else {
        sample_mlp_kernel<false><<<nblk, 256, 0, stream>>>(
            uv, vd, tex, nullptr, nullptr, W1, b1, W2, b2, W3, b3, out, nB);
    }
}

// Round 4
// 166.362 us; speedup vs baseline: 1.1361x; 1.0214x over previous
//
#include <hip/hip_runtime.h>
#include <hip/hip_bf16.h>

#define TT 2048
#define CC 8
#define R0 1023          // hot-region origin (uv in [0,1] -> taps in [1023,2047])
#define NRG 1025         // hot-region extent

// frag buffer layout (dword offsets) placed after wtex in d_ws
#define AF1 0            // 64 lanes x 4 dwords (8 bf16 A-frag, layer1)
#define AF2 256
#define AF3 512
#define CF1 768          // 64 lanes x 4 floats (C-init = bias)
#define CF2 1024
#define CF3 1280
#define FRDWORDS 1536

typedef short short8v __attribute__((ext_vector_type(8)));
typedef float float4v __attribute__((ext_vector_type(4)));
typedef float f2 __attribute__((ext_vector_type(2)));

static __device__ __forceinline__ unsigned short f2bf(float f) {
    __hip_bfloat16 b = __float2bfloat16(f);   // RNE
    return *reinterpret_cast<unsigned short*>(&b);
}
static __device__ __forceinline__ f2 bfp(unsigned u) {   // decode 2 packed bf16
    union { unsigned q; float f; } lo, hi;
    lo.q = u << 16; hi.q = u & 0xFFFF0000u;
    f2 r; r.x = lo.f; r.y = hi.f; return r;
}
static __device__ __forceinline__ unsigned cvtpk(float lo, float hi) {
    unsigned r;
    asm("v_cvt_pk_bf16_f32 %0, %1, %2" : "=v"(r) : "v"(lo), "v"(hi));
    return r;   // r[15:0]=bf16(lo), r[31:16]=bf16(hi), RNE
}
static __device__ __forceinline__ f2 fma2(f2 a, f2 b, f2 c) {
    f2 r; r.x = fmaf(a.x, b.x, c.x); r.y = fmaf(a.y, b.y, c.y); return r;
}

// ---------------- Kernel A: hot-region interleave+compress ----------------
__global__ __launch_bounds__(256) void interleave_kernel(
    const float* __restrict__ tex, unsigned short* __restrict__ wtex)
{
    int idx = blockIdx.x * 256 + threadIdx.x;
    if (idx >= NRG * NRG) return;
    int yy = idx / NRG;
    int xx = idx - yy * NRG;
    size_t src = (size_t)(R0 + yy) * TT + (size_t)(R0 + xx);
    union { unsigned short h[8]; uint4 u; } p;
#pragma unroll
    for (int c = 0; c < CC; ++c) p.h[c] = f2bf(tex[(size_t)c * (TT * TT) + src]);
    *reinterpret_cast<uint4*>(wtex + (size_t)idx * CC) = p.u;
}

// ---------------- Kernel A2: per-lane MFMA fragments for the MLP ----------
// A-frag (16x16x32): row = lane&15, k = (lane>>4)*8 + i  (bf16 x8 = 4 dwords)
// C-init           : row = (lane>>4)*4 + i, col = lane&15 -> bias[row]
__global__ __launch_bounds__(64) void prep_kernel(
    const float* __restrict__ W1, const float* __restrict__ b1,
    const float* __restrict__ W2, const float* __restrict__ b2,
    const float* __restrict__ W3, const float* __restrict__ b3,
    unsigned* __restrict__ fr)
{
    int L = threadIdx.x;
    if (L >= 64) return;
    int col = L & 15, kg = L >> 4;
    float* frf = reinterpret_cast<float*>(fr);
#pragma unroll
    for (int w = 0; w < 4; ++w) {
        int k0 = kg * 8 + 2 * w, k1 = k0 + 1;
        unsigned lo1 = (k0 < 11) ? f2bf(W1[col * 11 + k0]) : 0;
        unsigned hi1 = (k1 < 11) ? f2bf(W1[col * 11 + k1]) : 0;
        fr[AF1 + L * 4 + w] = lo1 | (hi1 << 16);
        unsigned lo2 = (k0 < 16) ? f2bf(W2[col * 16 + k0]) : 0;
        unsigned hi2 = (k1 < 16) ? f2bf(W2[col * 16 + k1]) : 0;
        fr[AF2 + L * 4 + w] = lo2 | (hi2 << 16);
        unsigned lo3 = (col < 3 && k0 < 16) ? f2bf(W3[col * 16 + k0]) : 0;
        unsigned hi3 = (col < 3 && k1 < 16) ? f2bf(W3[col * 16 + k1]) : 0;
        fr[AF3 + L * 4 + w] = lo3 | (hi3 << 16);
    }
#pragma unroll
    for (int i = 0; i < 4; ++i) {
        int r = kg * 4 + i;
        frf[CF1 + L * 4 + i] = b1[r];
        frf[CF2 + L * 4 + i] = b2[r];
        frf[CF3 + L * 4 + i] = (r < 3) ? b3[r] : 0.0f;
    }
}

// ---------------- shared helpers ----------------
static __device__ __forceinline__ bool fast_coords(float ux, float uy, int& o00, float w[4])
{
    float px = (ux + 1.0f) * 1023.5f;     // == ((u+1)*0.5)*(T-1), same rounding
    float py = (uy + 1.0f) * 1023.5f;
    float fx = floorf(px), fy = floorf(py);
    float wx1 = px - fx, wy1 = py - fy;
    float wx0 = 1.0f - wx1, wy0 = 1.0f - wy1;
    int x0 = (int)fx, y0 = (int)fy;
    w[0] = wy0 * wx0; w[1] = wy0 * wx1; w[2] = wy1 * wx0; w[3] = wy1 * wx1;
    o00 = (y0 - R0) * NRG + (x0 - R0);
    return (x0 >= R0) & (y0 >= R0) & (x0 < TT - 1) & (y0 < TT - 1);
}

static __device__ __forceinline__ void blend4(
    const uint4& A, const uint4& B, const uint4& C, const uint4& D,
    const float w[4], float feat[8])
{
    f2 w0, w1, w2, w3;
    w0.x = w0.y = w[0]; w1.x = w1.y = w[1]; w2.x = w2.y = w[2]; w3.x = w3.y = w[3];
    const unsigned* pa = reinterpret_cast<const unsigned*>(&A);
    const unsigned* pb = reinterpret_cast<const unsigned*>(&B);
    const unsigned* pc = reinterpret_cast<const unsigned*>(&C);
    const unsigned* pd = reinterpret_cast<const unsigned*>(&D);
#pragma unroll
    for (int c = 0; c < 4; ++c) {
        f2 r = bfp(pd[c]) * w3;
        r = fma2(bfp(pc[c]), w2, r);
        r = fma2(bfp(pb[c]), w1, r);
        r = fma2(bfp(pa[c]), w0, r);
        feat[2 * c] = r.x; feat[2 * c + 1] = r.y;
    }
}

// fully-general bilinear (zeros padding) from planar f32 texture
static __device__ __forceinline__ void gen_feat(
    const float* __restrict__ tex, float ux, float uy, float feat[8])
{
    float px = (ux + 1.0f) * 1023.5f;
    float py = (uy + 1.0f) * 1023.5f;
    float fx = floorf(px), fy = floorf(py);
    float wx1 = px - fx, wy1 = py - fy;
    float wx0 = 1.0f - wx1, wy0 = 1.0f - wy1;
    int x0 = (int)fx, y0 = (int)fy, x1 = x0 + 1, y1 = y0 + 1;
    float mx0 = (x0 >= 0 && x0 <= TT - 1) ? 1.0f : 0.0f;
    float mx1 = (x1 >= 0 && x1 <= TT - 1) ? 1.0f : 0.0f;
    float my0 = (y0 >= 0 && y0 <= TT - 1) ? 1.0f : 0.0f;
    float my1 = (y1 >= 0 && y1 <= TT - 1) ? 1.0f : 0.0f;
    int x0c = min(max(x0, 0), TT - 1), x1c = min(max(x1, 0), TT - 1);
    int y0c = min(max(y0, 0), TT - 1), y1c = min(max(y1, 0), TT - 1);
    float w00 = wy0 * wx0 * my0 * mx0, w01 = wy0 * wx1 * my0 * mx1;
    float w10 = wy1 * wx0 * my1 * mx0, w11 = wy1 * wx1 * my1 * mx1;
#pragma unroll
    for (int c = 0; c < CC; ++c) {
        const float* tp = tex + (size_t)c * (TT * TT);
        float a0 = tp[(size_t)y0c * TT + x0c];
        float b0 = tp[(size_t)y0c * TT + x1c];
        float c0 = tp[(size_t)y1c * TT + x0c];
        float d0 = tp[(size_t)y1c * TT + x1c];
        feat[c] = fmaf(w00, a0, fmaf(w01, b0, fmaf(w10, c0, w11 * d0)));
    }
}

static __device__ __forceinline__ void mlp_scalar(
    const float* __restrict__ W1, const float* __restrict__ b1,
    const float* __restrict__ W2, const float* __restrict__ b2,
    const float* __restrict__ W3, const float* __restrict__ b3,
    const float x[11], float rgb[3])
{
    float h1[16];
#pragma unroll
    for (int k = 0; k < 16; ++k) {
        float a = b1[k];
#pragma unroll
        for (int j = 0; j < 11; ++j) a = fmaf(x[j], W1[k * 11 + j], a);
        h1[k] = fmaxf(a, 0.0f);
    }
    float h2[16];
#pragma unroll
    for (int k = 0; k < 16; ++k) {
        float a = b2[k];
#pragma unroll
        for (int j = 0; j < 16; ++j) a = fmaf(h1[j], W2[k * 16 + j], a);
        h2[k] = fmaxf(a, 0.0f);
    }
#pragma unroll
    for (int k = 0; k < 3; ++k) {
        float a = b3[k];
#pragma unroll
        for (int j = 0; j < 16; ++j) a = fmaf(h2[j], W3[k * 16 + j], a);
        rgb[k] = __builtin_amdgcn_rcpf(1.0f + __expf(-a));
    }
}

union U4 { unsigned u[4]; short8v s; };

// ---------------- Kernel B (fast): gather + register-resident MFMA MLP ----
__global__ __launch_bounds__(256) void sample_mlp_mfma(
    const float* __restrict__ uv, const float* __restrict__ vd,
    const float* __restrict__ tex, const unsigned short* __restrict__ wtex,
    const unsigned* __restrict__ fr,
    float* __restrict__ out, long long nB)
{
    __shared__ unsigned xlds[4][64][12];   // 48B-stride rows, 12 KiB/block
    const int tid  = threadIdx.x;
    const int wave = tid >> 6, lane = tid & 63;
    const int col  = lane & 15, kg = lane >> 4;

    const long long blkbase = (long long)blockIdx.x * 256;
    const long long i = blkbase + tid;
    const bool act = (i < nB);

    // ---- per-sample xin = [bilinear feat(8), viewdirs(3)]
    float2 uvv = act ? *reinterpret_cast<const float2*>(uv + 2 * i)
                     : make_float2(-3.0f, -3.0f);
    float feat[8];
    {
        int o00; float w[4];
        if (fast_coords(uvv.x, uvv.y, o00, w)) {
            const uint4* base = reinterpret_cast<const uint4*>(wtex);
            uint4 t00 = base[o00],       t01 = base[o00 + 1];
            uint4 t10 = base[o00 + NRG], t11 = base[o00 + NRG + 1];
            blend4(t00, t01, t10, t11, w, feat);
        } else {
            gen_feat(tex, uvv.x, uvv.y, feat);
        }
    }
    float v0 = act ? vd[3 * i + 0] : 0.0f;
    float v1 = act ? vd[3 * i + 1] : 0.0f;
    float v2 = act ? vd[3 * i + 2] : 0.0f;

    // ---- pack xin to bf16 row (k=0..15, 11 real + zero pad) and stage in LDS
    {
        unsigned* rowp = &xlds[wave][lane][0];
        *reinterpret_cast<uint4*>(rowp) =
            make_uint4(cvtpk(feat[0], feat[1]), cvtpk(feat[2], feat[3]),
                       cvtpk(feat[4], feat[5]), cvtpk(feat[6], feat[7]));
        *reinterpret_cast<uint2*>(rowp + 4) = make_uint2(cvtpk(v0, v1), cvtpk(v2, 0.0f));
        *reinterpret_cast<uint2*>(rowp + 6) = make_uint2(0u, 0u);
    }

    // ---- per-lane weight fragments + bias C-init
    short8v a1 = *reinterpret_cast<const short8v*>(fr + AF1 + lane * 4);
    short8v a2 = *reinterpret_cast<const short8v*>(fr + AF2 + lane * 4);
    short8v a3 = *reinterpret_cast<const short8v*>(fr + AF3 + lane * 4);
    const float* frf = reinterpret_cast<const float*>(fr);
    float4v c1 = *reinterpret_cast<const float4v*>(frf + CF1 + lane * 4);
    float4v c2 = *reinterpret_cast<const float4v*>(frf + CF2 + lane * 4);
    float4v c3 = *reinterpret_cast<const float4v*>(frf + CF3 + lane * 4);

    __syncthreads();

    const unsigned* myrows = &xlds[wave][0][0];
    const int l16 = ((lane + 16) & 63) << 2;
    const int l32 = ((lane + 32) & 63) << 2;

#pragma unroll
    for (int g = 0; g < 4; ++g) {
        const int row = g * 16 + col;
        // layer 1 (K=32, k>=16 zero): B-frag from LDS, kg>=2 lanes all-zero
        short8v bfr = short8v{0, 0, 0, 0, 0, 0, 0, 0};
        if (kg < 2) bfr = *reinterpret_cast<const short8v*>(myrows + row * 12 + kg * 4);
        float4v d1 = __builtin_amdgcn_mfma_f32_16x16x32_bf16(a1, bfr, c1, 0, 0, 0);

        // relu + pack; regroup D rows (4/lane) into B k-slots (8/lane) via bpermute
        unsigned p0 = cvtpk(fmaxf(d1[0], 0.0f), fmaxf(d1[1], 0.0f));
        unsigned p1 = cvtpk(fmaxf(d1[2], 0.0f), fmaxf(d1[3], 0.0f));
        unsigned s0 = (unsigned)__builtin_amdgcn_ds_bpermute(l16, (int)p0);
        unsigned s1 = (unsigned)__builtin_amdgcn_ds_bpermute(l16, (int)p1);
        unsigned t0 = (unsigned)__builtin_amdgcn_ds_bpermute(l32, (int)p0);
        unsigned t1 = (unsigned)__builtin_amdgcn_ds_bpermute(l32, (int)p1);
        U4 bb;
        if (kg == 0)      { bb.u[0] = p0; bb.u[1] = p1; bb.u[2] = s0; bb.u[3] = s1; }
        else if (kg == 1) { bb.u[0] = s0; bb.u[1] = s1; bb.u[2] = t0; bb.u[3] = t1; }
        else              { bb.u[0] = 0;  bb.u[1] = 0;  bb.u[2] = 0;  bb.u[3] = 0;  }
        float4v d2 = __builtin_amdgcn_mfma_f32_16x16x32_bf16(a2, bb.s, c2, 0, 0, 0);

        unsigned q0 = cvtpk(fmaxf(d2[0], 0.0f), fmaxf(d2[1], 0.0f));
        unsigned q1 = cvtpk(fmaxf(d2[2], 0.0f), fmaxf(d2[3], 0.0f));
        unsigned u0 = (unsigned)__builtin_amdgcn_ds_bpermute(l16, (int)q0);
        unsigned u1 = (unsigned)__builtin_amdgcn_ds_bpermute(l16, (int)q1);
        unsigned w0 = (unsigned)__builtin_amdgcn_ds_bpermute(l32, (int)q0);
        unsigned w1 = (unsigned)__builtin_amdgcn_ds_bpermute(l32, (int)q1);
        U4 cb;
        if (kg == 0)      { cb.u[0] = q0; cb.u[1] = q1; cb.u[2] = u0; cb.u[3] = u1; }
        else if (kg == 1) { cb.u[0] = u0; cb.u[1] = u1; cb.u[2] = w0; cb.u[3] = w1; }
        else              { cb.u[0] = 0;  cb.u[1] = 0;  cb.u[2] = 0;  cb.u[3] = 0;  }
        float4v d3 = __builtin_amdgcn_mfma_f32_16x16x32_bf16(a3, cb.s, c3, 0, 0, 0);

        if (kg == 0) {   // lanes 0..15 hold rgb rows 0..2 of sample (g*16+col)
            long long sidx = blkbase + wave * 64 + row;
            if (sidx < nB) {
                out[3 * sidx + 0] = __builtin_amdgcn_rcpf(1.0f + __expf(-d3[0]));
                out[3 * sidx + 1] = __builtin_amdgcn_rcpf(1.0f + __expf(-d3[1]));
                out[3 * sidx + 2] = __builtin_amdgcn_rcpf(1.0f + __expf(-d3[2]));
            }
        }
    }
}

// ---------------- Kernel B (fallback, no workspace): scalar path ----------
__global__ __launch_bounds__(256) void sample_mlp_scalar(
    const float* __restrict__ uv, const float* __restrict__ vd,
    const float* __restrict__ tex,
    const float* __restrict__ W1, const float* __restrict__ b1,
    const float* __restrict__ W2, const float* __restrict__ b2,
    const float* __restrict__ W3, const float* __restrict__ b3,
    float* __restrict__ out, long long nB)
{
    long long i = (long long)blockIdx.x * 256 + threadIdx.x;
    if (i >= nB) return;
    float2 uvv = *reinterpret_cast<const float2*>(uv + 2 * i);
    float x[11];
    gen_feat(tex, uvv.x, uvv.y, x);
    x[8] = vd[3 * i]; x[9] = vd[3 * i + 1]; x[10] = vd[3 * i + 2];
    float rgb[3];
    mlp_scalar(W1, b1, W2, b2, W3, b3, x, rgb);
    out[3 * i] = rgb[0]; out[3 * i + 1] = rgb[1]; out[3 * i + 2] = rgb[2];
}

extern "C" void kernel_launch(void* const* d_in, const int* in_sizes, int n_in,
                              void* d_out, int out_size, void* d_ws, size_t ws_size,
                              hipStream_t stream)
{
    const float* uv  = (const float*)d_in[0];
    const float* vd  = (const float*)d_in[1];
    const float* tex = (const float*)d_in[2];
    const float* W1  = (const float*)d_in[3];
    const float* b1  = (const float*)d_in[4];
    const float* W2  = (const float*)d_in[5];
    const float* b2  = (const float*)d_in[6];
    const float* W3  = (const float*)d_in[7];
    const float* b3  = (const float*)d_in[8];
    float* out = (float*)d_out;
    long long nB = (long long)(in_sizes[0] / 2);

    const size_t wtexBytes = (size_t)NRG * NRG * CC * sizeof(unsigned short);  // 16.8 MB
    const size_t frOff = (wtexBytes + 255) & ~(size_t)255;
    const size_t need = frOff + FRDWORDS * sizeof(unsigned);
    int nblk = (int)((nB + 255) / 256);

    if (ws_size >= need) {
        unsigned short* wtex = (unsigned short*)d_ws;
        unsigned* fr = (unsigned*)((char*)d_ws + frOff);
        prep_kernel<<<1, 64, 0, stream>>>(W1, b1, W2, b2, W3, b3, fr);
        interleave_kernel<<<(NRG * NRG + 255) / 256, 256, 0, stream>>>(tex, wtex);
        sample_mlp_mfma<<<nblk, 256, 0, stream>>>(uv, vd, tex, wtex, fr, out, nB);
    } else {
        sample_mlp_scalar<<<nblk, 256, 0, stream>>>(
            uv, vd, tex, W1, b1, W2, b2, W3, b3, out, nB);
    }
}

// Round 5
// 131.551 us; speedup vs baseline: 1.4368x; 1.2646x over previous
//
#include <hip/hip_runtime.h>
#include <hip/hip_bf16.h>

#define TT 2048
#define CC 8
#define R0 1023          // hot-region origin (uv in [0,1] -> taps in [1023,2047])
#define NRG 1025         // texel-table extent (tier-1 fallback)
#define NQ 1024          // quad-table extent (1024 x 1024 cells)

// frag buffer layout (dword offsets) at d_ws+0; tables at d_ws+8192
#define AF1 0
#define AF2 256
#define AF3 512
#define CF1 768
#define CF2 1024
#define CF3 1280
#define FRDWORDS 1536
#define TBLOFF 8192

typedef short short8v __attribute__((ext_vector_type(8)));
typedef float float4v __attribute__((ext_vector_type(4)));
typedef float f2 __attribute__((ext_vector_type(2)));

static __device__ __forceinline__ unsigned short f2bf(float f) {
    __hip_bfloat16 b = __float2bfloat16(f);   // RNE
    return *reinterpret_cast<unsigned short*>(&b);
}
static __device__ __forceinline__ f2 bfp(unsigned u) {   // decode 2 packed bf16
    union { unsigned q; float f; } lo, hi;
    lo.q = u << 16; hi.q = u & 0xFFFF0000u;
    f2 r; r.x = lo.f; r.y = hi.f; return r;
}
static __device__ __forceinline__ unsigned cvtpk(float lo, float hi) {
    unsigned r;
    asm("v_cvt_pk_bf16_f32 %0, %1, %2" : "=v"(r) : "v"(lo), "v"(hi));
    return r;
}
static __device__ __forceinline__ f2 fma2(f2 a, f2 b, f2 c) {
    f2 r; r.x = fmaf(a.x, b.x, c.x); r.y = fmaf(a.y, b.y, c.y); return r;
}

// ---------------- Kernel A2: per-lane MFMA fragments for the MLP ----------
__global__ __launch_bounds__(64) void prep_kernel(
    const float* __restrict__ W1, const float* __restrict__ b1,
    const float* __restrict__ W2, const float* __restrict__ b2,
    const float* __restrict__ W3, const float* __restrict__ b3,
    unsigned* __restrict__ fr)
{
    int L = threadIdx.x;
    if (L >= 64) return;
    int col = L & 15, kg = L >> 4;
    float* frf = reinterpret_cast<float*>(fr);
#pragma unroll
    for (int w = 0; w < 4; ++w) {
        int k0 = kg * 8 + 2 * w, k1 = k0 + 1;
        unsigned lo1 = (k0 < 11) ? f2bf(W1[col * 11 + k0]) : 0;
        unsigned hi1 = (k1 < 11) ? f2bf(W1[col * 11 + k1]) : 0;
        fr[AF1 + L * 4 + w] = lo1 | (hi1 << 16);
        unsigned lo2 = (k0 < 16) ? f2bf(W2[col * 16 + k0]) : 0;
        unsigned hi2 = (k1 < 16) ? f2bf(W2[col * 16 + k1]) : 0;
        fr[AF2 + L * 4 + w] = lo2 | (hi2 << 16);
        unsigned lo3 = (col < 3 && k0 < 16) ? f2bf(W3[col * 16 + k0]) : 0;
        unsigned hi3 = (col < 3 && k1 < 16) ? f2bf(W3[col * 16 + k1]) : 0;
        fr[AF3 + L * 4 + w] = lo3 | (hi3 << 16);
    }
#pragma unroll
    for (int i = 0; i < 4; ++i) {
        int r = kg * 4 + i;
        frf[CF1 + L * 4 + i] = b1[r];
        frf[CF2 + L * 4 + i] = b2[r];
        frf[CF3 + L * 4 + i] = (r < 3) ? b3[r] : 0.0f;
    }
}

// ---------------- Kernel A (tier 2): quad-record table ---------------------
// record[cell=(y0-R0)*1024+(x0-R0)] = [t00(8), t01(8), t10(8), t11(8)] bf16 = 64B
__global__ __launch_bounds__(256) void quadbuild_kernel(
    const float* __restrict__ tex, unsigned short* __restrict__ qtex)
{
    int idx = blockIdx.x * 256 + threadIdx.x;
    if (idx >= NQ * NQ) return;
    int qy = idx >> 10, qx = idx & (NQ - 1);
    size_t y = (size_t)(R0 + qy), x = (size_t)(R0 + qx);
    unsigned short h[32];
#pragma unroll
    for (int c = 0; c < CC; ++c) {
        const float* tp = tex + (size_t)c * (TT * TT);
        h[c]      = f2bf(tp[y * TT + x]);
        h[8 + c]  = f2bf(tp[y * TT + x + 1]);
        h[16 + c] = f2bf(tp[(y + 1) * TT + x]);
        h[24 + c] = f2bf(tp[(y + 1) * TT + x + 1]);
    }
    uint4* dst = reinterpret_cast<uint4*>(qtex) + (size_t)idx * 4;
    const uint4* src = reinterpret_cast<const uint4*>(h);
#pragma unroll
    for (int k = 0; k < 4; ++k) dst[k] = src[k];
}

// ---------------- Kernel A (tier 1): texel-record table --------------------
__global__ __launch_bounds__(256) void interleave_kernel(
    const float* __restrict__ tex, unsigned short* __restrict__ wtex)
{
    int idx = blockIdx.x * 256 + threadIdx.x;
    if (idx >= NRG * NRG) return;
    int yy = idx / NRG;
    int xx = idx - yy * NRG;
    size_t src = (size_t)(R0 + yy) * TT + (size_t)(R0 + xx);
    union { unsigned short h[8]; uint4 u; } p;
#pragma unroll
    for (int c = 0; c < CC; ++c) p.h[c] = f2bf(tex[(size_t)c * (TT * TT) + src]);
    *reinterpret_cast<uint4*>(wtex + (size_t)idx * CC) = p.u;
}

// ---------------- shared helpers ----------------
static __device__ __forceinline__ void blend4(
    const uint4& A, const uint4& B, const uint4& C, const uint4& D,
    const float w[4], float feat[8])
{
    f2 w0, w1, w2, w3;
    w0.x = w0.y = w[0]; w1.x = w1.y = w[1]; w2.x = w2.y = w[2]; w3.x = w3.y = w[3];
    const unsigned* pa = reinterpret_cast<const unsigned*>(&A);
    const unsigned* pb = reinterpret_cast<const unsigned*>(&B);
    const unsigned* pc = reinterpret_cast<const unsigned*>(&C);
    const unsigned* pd = reinterpret_cast<const unsigned*>(&D);
#pragma unroll
    for (int c = 0; c < 4; ++c) {
        f2 r = bfp(pd[c]) * w3;
        r = fma2(bfp(pc[c]), w2, r);
        r = fma2(bfp(pb[c]), w1, r);
        r = fma2(bfp(pa[c]), w0, r);
        feat[2 * c] = r.x; feat[2 * c + 1] = r.y;
    }
}

// fully-general bilinear (zeros padding) from planar f32 texture
static __device__ __forceinline__ void gen_feat(
    const float* __restrict__ tex, float ux, float uy, float feat[8])
{
    float px = (ux + 1.0f) * 1023.5f;
    float py = (uy + 1.0f) * 1023.5f;
    float fx = floorf(px), fy = floorf(py);
    float wx1 = px - fx, wy1 = py - fy;
    float wx0 = 1.0f - wx1, wy0 = 1.0f - wy1;
    int x0 = (int)fx, y0 = (int)fy, x1 = x0 + 1, y1 = y0 + 1;
    float mx0 = (x0 >= 0 && x0 <= TT - 1) ? 1.0f : 0.0f;
    float mx1 = (x1 >= 0 && x1 <= TT - 1) ? 1.0f : 0.0f;
    float my0 = (y0 >= 0 && y0 <= TT - 1) ? 1.0f : 0.0f;
    float my1 = (y1 >= 0 && y1 <= TT - 1) ? 1.0f : 0.0f;
    int x0c = min(max(x0, 0), TT - 1), x1c = min(max(x1, 0), TT - 1);
    int y0c = min(max(y0, 0), TT - 1), y1c = min(max(y1, 0), TT - 1);
    float w00 = wy0 * wx0 * my0 * mx0, w01 = wy0 * wx1 * my0 * mx1;
    float w10 = wy1 * wx0 * my1 * mx0, w11 = wy1 * wx1 * my1 * mx1;
#pragma unroll
    for (int c = 0; c < CC; ++c) {
        const float* tp = tex + (size_t)c * (TT * TT);
        float a0 = tp[(size_t)y0c * TT + x0c];
        float b0 = tp[(size_t)y0c * TT + x1c];
        float c0 = tp[(size_t)y1c * TT + x0c];
        float d0 = tp[(size_t)y1c * TT + x1c];
        feat[c] = fmaf(w00, a0, fmaf(w01, b0, fmaf(w10, c0, w11 * d0)));
    }
}

static __device__ __forceinline__ void mlp_scalar(
    const float* __restrict__ W1, const float* __restrict__ b1,
    const float* __restrict__ W2, const float* __restrict__ b2,
    const float* __restrict__ W3, const float* __restrict__ b3,
    const float x[11], float rgb[3])
{
    float h1[16];
#pragma unroll
    for (int k = 0; k < 16; ++k) {
        float a = b1[k];
#pragma unroll
        for (int j = 0; j < 11; ++j) a = fmaf(x[j], W1[k * 11 + j], a);
        h1[k] = fmaxf(a, 0.0f);
    }
    float h2[16];
#pragma unroll
    for (int k = 0; k < 16; ++k) {
        float a = b2[k];
#pragma unroll
        for (int j = 0; j < 16; ++j) a = fmaf(h1[j], W2[k * 16 + j], a);
        h2[k] = fmaxf(a, 0.0f);
    }
#pragma unroll
    for (int k = 0; k < 3; ++k) {
        float a = b3[k];
#pragma unroll
        for (int j = 0; j < 16; ++j) a = fmaf(h2[j], W3[k * 16 + j], a);
        rgb[k] = __builtin_amdgcn_rcpf(1.0f + __expf(-a));
    }
}

union U4 { unsigned u[4]; short8v s; };

// ---------------- Kernel B: gather + register-resident MFMA MLP -----------
// GM == 0: quad-record table (one 64B line per sample)
// GM == 1: texel-record table (4 x 16B gathers)
template <int GM>
__global__ __launch_bounds__(256) void sample_mlp_mfma(
    const float* __restrict__ uv, const float* __restrict__ vd,
    const float* __restrict__ tex,
    const unsigned short* __restrict__ wtex,   // texel table (GM==1)
    const unsigned short* __restrict__ qtex,   // quad table  (GM==0)
    const unsigned* __restrict__ fr,
    float* __restrict__ out, long long nB)
{
    __shared__ unsigned xlds[4][64][12];   // 48B-stride rows, 12 KiB/block
    const int tid  = threadIdx.x;
    const int wave = tid >> 6, lane = tid & 63;
    const int col  = lane & 15, kg = lane >> 4;

    const long long blkbase = (long long)blockIdx.x * 256;
    const long long i = blkbase + tid;
    const bool act = (i < nB);

    // ---- streaming inputs (nontemporal: keep L2 for the gather table)
    f2 uvv;
    if (act) uvv = __builtin_nontemporal_load(reinterpret_cast<const f2*>(uv + 2 * i));
    else { uvv.x = -3.0f; uvv.y = -3.0f; }
    float v0 = act ? __builtin_nontemporal_load(vd + 3 * i + 0) : 0.0f;
    float v1 = act ? __builtin_nontemporal_load(vd + 3 * i + 1) : 0.0f;
    float v2 = act ? __builtin_nontemporal_load(vd + 3 * i + 2) : 0.0f;

    // ---- bilinear coordinates
    float px = (uvv.x + 1.0f) * 1023.5f;   // == ((u+1)*0.5)*(T-1)
    float py = (uvv.y + 1.0f) * 1023.5f;
    float fx = floorf(px), fy = floorf(py);
    float wx1 = px - fx, wy1 = py - fy;
    float wx0 = 1.0f - wx1, wy0 = 1.0f - wy1;
    int x0 = (int)fx, y0 = (int)fy;
    float w[4] = { wy0 * wx0, wy0 * wx1, wy1 * wx0, wy1 * wx1 };
    const bool inr = (x0 >= R0) & (y0 >= R0) & (x0 < TT - 1) & (y0 < TT - 1);

    float feat[8];
    if (inr) {
        if (GM == 0) {
            size_t cell = ((size_t)(unsigned)(y0 - R0) << 10) | (unsigned)(x0 - R0);
            const uint4* q = reinterpret_cast<const uint4*>(qtex) + cell * 4;
            uint4 t00 = q[0], t01 = q[1], t10 = q[2], t11 = q[3];   // one 64B line
            blend4(t00, t01, t10, t11, w, feat);
        } else {
            int o00 = (y0 - R0) * NRG + (x0 - R0);
            const uint4* base = reinterpret_cast<const uint4*>(wtex);
            uint4 t00 = base[o00],       t01 = base[o00 + 1];
            uint4 t10 = base[o00 + NRG], t11 = base[o00 + NRG + 1];
            blend4(t00, t01, t10, t11, w, feat);
        }
    } else {
        gen_feat(tex, uvv.x, uvv.y, feat);
    }

    // ---- pack xin row (k=0..15: 8 feat + 3 vd + zero pad) into LDS
    {
        unsigned* rowp = &xlds[wave][lane][0];
        *reinterpret_cast<uint4*>(rowp) =
            make_uint4(cvtpk(feat[0], feat[1]), cvtpk(feat[2], feat[3]),
                       cvtpk(feat[4], feat[5]), cvtpk(feat[6], feat[7]));
        *reinterpret_cast<uint2*>(rowp + 4) = make_uint2(cvtpk(v0, v1), cvtpk(v2, 0.0f));
        *reinterpret_cast<uint2*>(rowp + 6) = make_uint2(0u, 0u);
    }

    // ---- per-lane weight fragments + bias C-init
    short8v a1 = *reinterpret_cast<const short8v*>(fr + AF1 + lane * 4);
    short8v a2 = *reinterpret_cast<const short8v*>(fr + AF2 + lane * 4);
    short8v a3 = *reinterpret_cast<const short8v*>(fr + AF3 + lane * 4);
    const float* frf = reinterpret_cast<const float*>(fr);
    float4v c1 = *reinterpret_cast<const float4v*>(frf + CF1 + lane * 4);
    float4v c2 = *reinterpret_cast<const float4v*>(frf + CF2 + lane * 4);
    float4v c3 = *reinterpret_cast<const float4v*>(frf + CF3 + lane * 4);

    __syncthreads();

    const unsigned* myrows = &xlds[wave][0][0];
    const int l16 = ((lane + 16) & 63) << 2;
    const int l32 = ((lane + 32) & 63) << 2;

#pragma unroll
    for (int g = 0; g < 4; ++g) {
        const int row = g * 16 + col;
        short8v bfr = short8v{0, 0, 0, 0, 0, 0, 0, 0};
        if (kg < 2) bfr = *reinterpret_cast<const short8v*>(myrows + row * 12 + kg * 4);
        float4v d1 = __builtin_amdgcn_mfma_f32_16x16x32_bf16(a1, bfr, c1, 0, 0, 0);

        unsigned p0 = cvtpk(fmaxf(d1[0], 0.0f), fmaxf(d1[1], 0.0f));
        unsigned p1 = cvtpk(fmaxf(d1[2], 0.0f), fmaxf(d1[3], 0.0f));
        unsigned s0 = (unsigned)__builtin_amdgcn_ds_bpermute(l16, (int)p0);
        unsigned s1 = (unsigned)__builtin_amdgcn_ds_bpermute(l16, (int)p1);
        unsigned t0 = (unsigned)__builtin_amdgcn_ds_bpermute(l32, (int)p0);
        unsigned t1 = (unsigned)__builtin_amdgcn_ds_bpermute(l32, (int)p1);
        U4 bb;
        if (kg == 0)      { bb.u[0] = p0; bb.u[1] = p1; bb.u[2] = s0; bb.u[3] = s1; }
        else if (kg == 1) { bb.u[0] = s0; bb.u[1] = s1; bb.u[2] = t0; bb.u[3] = t1; }
        else              { bb.u[0] = 0;  bb.u[1] = 0;  bb.u[2] = 0;  bb.u[3] = 0;  }
        float4v d2 = __builtin_amdgcn_mfma_f32_16x16x32_bf16(a2, bb.s, c2, 0, 0, 0);

        unsigned q0 = cvtpk(fmaxf(d2[0], 0.0f), fmaxf(d2[1], 0.0f));
        unsigned q1 = cvtpk(fmaxf(d2[2], 0.0f), fmaxf(d2[3], 0.0f));
        unsigned u0 = (unsigned)__builtin_amdgcn_ds_bpermute(l16, (int)q0);
        unsigned u1 = (unsigned)__builtin_amdgcn_ds_bpermute(l16, (int)q1);
        unsigned w0 = (unsigned)__builtin_amdgcn_ds_bpermute(l32, (int)q0);
        unsigned w1 = (unsigned)__builtin_amdgcn_ds_bpermute(l32, (int)q1);
        U4 cb;
        if (kg == 0)      { cb.u[0] = q0; cb.u[1] = q1; cb.u[2] = u0; cb.u[3] = u1; }
        else if (kg == 1) { cb.u[0] = u0; cb.u[1] = u1; cb.u[2] = w0; cb.u[3] = w1; }
        else              { cb.u[0] = 0;  cb.u[1] = 0;  cb.u[2] = 0;  cb.u[3] = 0;  }
        float4v d3 = __builtin_amdgcn_mfma_f32_16x16x32_bf16(a3, cb.s, c3, 0, 0, 0);

        if (kg == 0) {   // lanes 0..15 hold rgb rows 0..2 of sample (g*16+col)
            long long sidx = blkbase + wave * 64 + row;
            if (sidx < nB) {
                __builtin_nontemporal_store(__builtin_amdgcn_rcpf(1.0f + __expf(-d3[0])), out + 3 * sidx + 0);
                __builtin_nontemporal_store(__builtin_amdgcn_rcpf(1.0f + __expf(-d3[1])), out + 3 * sidx + 1);
                __builtin_nontemporal_store(__builtin_amdgcn_rcpf(1.0f + __expf(-d3[2])), out + 3 * sidx + 2);
            }
        }
    }
}

// ---------------- Kernel B (fallback, no workspace): scalar path ----------
__global__ __launch_bounds__(256) void sample_mlp_scalar(
    const float* __restrict__ uv, const float* __restrict__ vd,
    const float* __restrict__ tex,
    const float* __restrict__ W1, const float* __restrict__ b1,
    const float* __restrict__ W2, const float* __restrict__ b2,
    const float* __restrict__ W3, const float* __restrict__ b3,
    float* __restrict__ out, long long nB)
{
    long long i = (long long)blockIdx.x * 256 + threadIdx.x;
    if (i >= nB) return;
    float2 uvv = *reinterpret_cast<const float2*>(uv + 2 * i);
    float x[11];
    gen_feat(tex, uvv.x, uvv.y, x);
    x[8] = vd[3 * i]; x[9] = vd[3 * i + 1]; x[10] = vd[3 * i + 2];
    float rgb[3];
    mlp_scalar(W1, b1, W2, b2, W3, b3, x, rgb);
    out[3 * i] = rgb[0]; out[3 * i + 1] = rgb[1]; out[3 * i + 2] = rgb[2];
}

extern "C" void kernel_launch(void* const* d_in, const int* in_sizes, int n_in,
                              void* d_out, int out_size, void* d_ws, size_t ws_size,
                              hipStream_t stream)
{
    const float* uv  = (const float*)d_in[0];
    const float* vd  = (const float*)d_in[1];
    const float* tex = (const float*)d_in[2];
    const float* W1  = (const float*)d_in[3];
    const float* b1  = (const float*)d_in[4];
    const float* W2  = (const float*)d_in[5];
    const float* b2  = (const float*)d_in[6];
    const float* W3  = (const float*)d_in[7];
    const float* b3  = (const float*)d_in[8];
    float* out = (float*)d_out;
    long long nB = (long long)(in_sizes[0] / 2);

    const size_t needQ = TBLOFF + (size_t)NQ * NQ * 64;            // ~67.1 MB
    const size_t needT = TBLOFF + (size_t)NRG * NRG * CC * 2;      // ~16.8 MB
    int nblk = (int)((nB + 255) / 256);

    if (ws_size >= needQ) {
        unsigned* fr = (unsigned*)d_ws;
        unsigned short* qtex = (unsigned short*)((char*)d_ws + TBLOFF);
        prep_kernel<<<1, 64, 0, stream>>>(W1, b1, W2, b2, W3, b3, fr);
        quadbuild_kernel<<<(NQ * NQ) / 256, 256, 0, stream>>>(tex, qtex);
        sample_mlp_mfma<0><<<nblk, 256, 0, stream>>>(
            uv, vd, tex, nullptr, qtex, fr, out, nB);
    } else if (ws_size >= needT) {
        unsigned* fr = (unsigned*)d_ws;
        unsigned short* wtex = (unsigned short*)((char*)d_ws + TBLOFF);
        prep_kernel<<<1, 64, 0, stream>>>(W1, b1, W2, b2, W3, b3, fr);
        interleave_kernel<<<(NRG * NRG + 255) / 256, 256, 0, stream>>>(tex, wtex);
        sample_mlp_mfma<1><<<nblk, 256, 0, stream>>>(
            uv, vd, tex, wtex, nullptr, fr, out, nB);
    } else {
        sample_mlp_scalar<<<nblk, 256, 0, stream>>>(
            uv, vd, tex, W1, b1, W2, b2, W3, b3, out, nB);
    }
}